// Round 4
// baseline (3559.509 us; speedup 1.0000x reference)
//
#include <hip/hip_runtime.h>

// Att_RNN_GRU: B=128, T=1024, I=128, H=256 (3H=768), A=40
// Phase 1: gx = x @ W_ih^T + b_ih + [b_hh for r,z cols]  -> f16 [B*T, 768]
// Phase 2: GRU recurrence via MFMA: 8 blocks x 16 batches, 512 thr (8 waves).
//          Per step: gh^T[768x16] = W_hh[768x256] . h^T[256x16] with
//          v_mfma_f32_16x16x32_f16. W_hh register-resident (192 VGPR/lane,
//          1 block/CU so budget is ~512). Wave w owns gate cols [32w,32w+32)
//          for r,z,n -> gate math in-register. h^T in LDS, k-chunked
//          [32][16][8]f16 layout (2-way max bank aliasing = free).
//          h_t overwrites gx row (b,t)[0:256].
// Phase 3a: s[b,t] = wu . tanh(wv_W @ out + wv_b)   (outs = gx rows, stride 768)
// Phase 3b: softmax over t, context, out = context @ h2o_W^T + b
//
// Workspace: s @0 (512KB), Wp @524288 (384KB), gx @917504 (192MB) = 202.2MB

#define B_ 128
#define T_ 1024
#define I_ 128
#define H_ 256
#define G_ 768
#define A_ 40

typedef _Float16 f16;
typedef _Float16 f16x2 __attribute__((ext_vector_type(2)));
typedef _Float16 f16x4 __attribute__((ext_vector_type(4)));
typedef _Float16 f16x8 __attribute__((ext_vector_type(8)));
typedef float    f32x4 __attribute__((ext_vector_type(4)));

__device__ __forceinline__ float fdot2(unsigned a, unsigned b, float c){
#if __has_builtin(__builtin_amdgcn_fdot2)
  return __builtin_amdgcn_fdot2(__builtin_bit_cast(f16x2, a),
                                __builtin_bit_cast(f16x2, b), c, false);
#else
  f16x2 av = __builtin_bit_cast(f16x2, a), bv = __builtin_bit_cast(f16x2, b);
  return c + (float)av.x * (float)bv.x + (float)av.y * (float)bv.y;
#endif
}

__device__ __forceinline__ float2 h2f(unsigned u){
  f16x2 h = __builtin_bit_cast(f16x2, u);
  return make_float2((float)h.x, (float)h.y);
}
__device__ __forceinline__ unsigned f2h2(float a, float b){
  f16x2 h; h.x = (f16)a; h.y = (f16)b;
  return __builtin_bit_cast(unsigned, h);
}
__device__ __forceinline__ float sigm_(float x){ return 1.f / (1.f + __expf(-x)); }
__device__ __forceinline__ float tanh_(float x){ return 1.f - 2.f / (__expf(2.f * x) + 1.f); }

// ---------------------------------------------------------------- prep W_hh
// W_hh fp32 [768][256] -> f16 A-fragments for mfma_f32_16x16x32_f16.
// Fragment (nt, kt): lane l holds W[16*nt + (l&15)][32*kt + 8*(l>>4) + i], i=0..7.
// Flat f16 index: ((nt*8 + kt)*64 + l)*8 + i.
__global__ __launch_bounds__(256) void k_prep_w(const float* __restrict__ W,
                                                unsigned* __restrict__ Wp){
  int u = blockIdx.x * 256 + threadIdx.x;        // uint index, 0..98303
  int i2 = u & 3;                                // f16-pair within lane
  int l  = (u >> 2) & 63;
  int kt = (u >> 8) & 7;
  int nt = u >> 11;                              // 0..47
  int n = nt * 16 + (l & 15);
  int k = kt * 32 + (l >> 4) * 8 + i2 * 2;
  Wp[u] = f2h2(W[n * 256 + k], W[n * 256 + k + 1]);
}

// ---------------------------------------------------------------- phase 1
// gx[m][n] = sum_k x[m][k]*W_ih[n][k] + b_ih[n] + (n<512 ? b_hh[n] : 0)
__global__ __launch_bounds__(256) void k_gx(const float* __restrict__ x,
                                            const float* __restrict__ wih,
                                            const float* __restrict__ bih,
                                            const float* __restrict__ bhh,
                                            unsigned* __restrict__ gx){
  __shared__ __align__(16) unsigned Au[32 * 68];   // [kpair][row], pad 68
  __shared__ __align__(16) unsigned Bu[32 * 68];
  const int tid = threadIdx.x;
  const int m0 = blockIdx.x * 64, n0 = blockIdx.y * 64;
  const int ar = tid >> 4, bc = tid & 15;
  float acc[4][4] = {{0.f}};

  for (int kh = 0; kh < 2; ++kh){
    __syncthreads();
    #pragma unroll
    for (int u = 0; u < 4; ++u){
      int idx = tid + 256 * u;
      int row = idx >> 4;
      int kq  = idx & 15;
      float4 va = *(const float4*)(x   + (size_t)(m0 + row) * I_ + kh * 64 + kq * 4);
      float4 vb = *(const float4*)(wih + (size_t)(n0 + row) * I_ + kh * 64 + kq * 4);
      Au[(2*kq  ) * 68 + row] = f2h2(va.x, va.y);
      Au[(2*kq+1) * 68 + row] = f2h2(va.z, va.w);
      Bu[(2*kq  ) * 68 + row] = f2h2(vb.x, vb.y);
      Bu[(2*kq+1) * 68 + row] = f2h2(vb.z, vb.w);
    }
    __syncthreads();
    #pragma unroll 8
    for (int kp = 0; kp < 32; ++kp){
      uint4 a4 = *(const uint4*)(Au + kp * 68 + ar * 4);
      uint4 b4 = *(const uint4*)(Bu + kp * 68 + bc * 4);
      acc[0][0]=fdot2(a4.x,b4.x,acc[0][0]); acc[0][1]=fdot2(a4.x,b4.y,acc[0][1]);
      acc[0][2]=fdot2(a4.x,b4.z,acc[0][2]); acc[0][3]=fdot2(a4.x,b4.w,acc[0][3]);
      acc[1][0]=fdot2(a4.y,b4.x,acc[1][0]); acc[1][1]=fdot2(a4.y,b4.y,acc[1][1]);
      acc[1][2]=fdot2(a4.y,b4.z,acc[1][2]); acc[1][3]=fdot2(a4.y,b4.w,acc[1][3]);
      acc[2][0]=fdot2(a4.z,b4.x,acc[2][0]); acc[2][1]=fdot2(a4.z,b4.y,acc[2][1]);
      acc[2][2]=fdot2(a4.z,b4.z,acc[2][2]); acc[2][3]=fdot2(a4.z,b4.w,acc[2][3]);
      acc[3][0]=fdot2(a4.w,b4.x,acc[3][0]); acc[3][1]=fdot2(a4.w,b4.y,acc[3][1]);
      acc[3][2]=fdot2(a4.w,b4.z,acc[3][2]); acc[3][3]=fdot2(a4.w,b4.w,acc[3][3]);
    }
  }

  float bn[4];
  #pragma unroll
  for (int j = 0; j < 4; ++j){
    int n = n0 + bc * 4 + j;
    bn[j] = bih[n] + (n < 512 ? bhh[n] : 0.f);   // fold b_hh for r,z gates
  }
  #pragma unroll
  for (int i = 0; i < 4; ++i){
    int m = m0 + ar * 4 + i;
    uint2 st;
    st.x = f2h2(acc[i][0] + bn[0], acc[i][1] + bn[1]);
    st.y = f2h2(acc[i][2] + bn[2], acc[i][3] + bn[3]);
    *(uint2*)(gx + (size_t)m * (G_ / 2) + n0 / 2 + bc * 2) = st;
  }
}

// ---------------------------------------------------------------- phase 2
// 8 blocks x 16 batches, 512 threads (8 waves). Per step, wave w computes
// gh^T tiles nt in {2w,2w+1} (r), {+16} (z), {+32} (n) via 6x8 mfma; C layout:
// batch m = lane&15, gate col (within tile) = (lane>>4)*4 + j. h^T in LDS,
// k-chunked [chunk=k>>3][m][k&7] f16 (16B rows), double-buffered.
__global__ __launch_bounds__(512, 1) void k_gru(const uint4* __restrict__ Wp4,
                                                unsigned* __restrict__ gx,
                                                const float* __restrict__ bhh){
  __shared__ uint4 hbuf[2][512];                 // 2 x 8KB
  const int tid = threadIdx.x;
  const int w = tid >> 6, l = tid & 63;
  const int q = l >> 4, m = l & 15;
  const int b0 = blockIdx.x * 16;
  const int cb0 = 32 * w + 4 * q;                // p=0 col base; p=1 adds 16

  // W_hh fragments: 6 tiles x 8 k-tiles, register-resident (192 VGPR)
  uint4 Wf[6][8];
  const int ntb[6] = {2*w, 2*w+1, 16+2*w, 17+2*w, 32+2*w, 33+2*w};
  #pragma unroll
  for (int tt = 0; tt < 6; ++tt)
    #pragma unroll
    for (int kt = 0; kt < 8; ++kt)
      Wf[tt][kt] = Wp4[(ntb[tt] * 8 + kt) * 64 + l];

  // b_hh for the n-gate (not foldable: multiplied by r)
  float bn0[4], bn1[4];
  #pragma unroll
  for (int j = 0; j < 4; ++j){
    bn0[j] = bhh[512 + cb0 + j];
    bn1[j] = bhh[512 + cb0 + 16 + j];
  }

  f16* gxw = (f16*)gx;
  const size_t rbase = (size_t)(b0 + m) * T_;

  // x-terms for t=0 (r,z pre-biased; 4 consecutive f16 = 8B per gate per p)
  const f16* x0 = gxw + rbase * G_;
  uint2 xr0 = *(const uint2*)(x0 + cb0),       xr1 = *(const uint2*)(x0 + cb0 + 16);
  uint2 xz0 = *(const uint2*)(x0 + 256 + cb0), xz1 = *(const uint2*)(x0 + 256 + cb0 + 16);
  uint2 xn0 = *(const uint2*)(x0 + 512 + cb0), xn1 = *(const uint2*)(x0 + 512 + cb0 + 16);

  hbuf[0][tid] = make_uint4(0, 0, 0, 0);         // h(-1) = 0
  float hprev[2][4] = {{0.f}};
  __syncthreads();

  int cur = 0;
  for (int t = 0; t < T_; ++t){
    // prefetch next step's x-terms (consumed after barrier)
    uint2 pr0, pz0, pn0, pr1, pz1, pn1;
    if (t + 1 < T_){
      const f16* nx = gxw + (rbase + t + 1) * G_;
      pr0 = *(const uint2*)(nx + cb0);       pr1 = *(const uint2*)(nx + cb0 + 16);
      pz0 = *(const uint2*)(nx + 256 + cb0); pz1 = *(const uint2*)(nx + 256 + cb0 + 16);
      pn0 = *(const uint2*)(nx + 512 + cb0); pn1 = *(const uint2*)(nx + 512 + cb0 + 16);
    } else {
      pr0=pz0=pn0=pr1=pz1=pn1=make_uint2(0,0);
    }

    // B-fragments of h^T: lane reads h[m][32kt+8q .. +7] = 16B
    uint4 bf[8];
    #pragma unroll
    for (int kt = 0; kt < 8; ++kt)
      bf[kt] = hbuf[cur][(4 * kt + q) * 16 + m];

    f32x4 acc[6];
    #pragma unroll
    for (int tt = 0; tt < 6; ++tt) acc[tt] = (f32x4){0.f, 0.f, 0.f, 0.f};
    #pragma unroll
    for (int kt = 0; kt < 8; ++kt){
      f16x8 bv = __builtin_bit_cast(f16x8, bf[kt]);
      #pragma unroll
      for (int tt = 0; tt < 6; ++tt)
        acc[tt] = __builtin_amdgcn_mfma_f32_16x16x32_f16(
            __builtin_bit_cast(f16x8, Wf[tt][kt]), bv, acc[tt], 0, 0, 0);
    }

    // gate math: p=0 -> acc[0]/acc[2]/acc[4], p=1 -> acc[1]/acc[3]/acc[5]
    uint2* hnext2 = (uint2*)hbuf[cur ^ 1];
    f16*   orow   = gxw + (rbase + t) * G_;
    #pragma unroll
    for (int p = 0; p < 2; ++p){
      f16x4 xrv = __builtin_bit_cast(f16x4, p ? xr1 : xr0);
      f16x4 xzv = __builtin_bit_cast(f16x4, p ? xz1 : xz0);
      f16x4 xnv = __builtin_bit_cast(f16x4, p ? xn1 : xn0);
      const float* bnv = p ? bn1 : bn0;
      f32x4 aR = acc[0 + p], aZ = acc[2 + p], aN = acc[4 + p];
      float hh[4];
      #pragma unroll
      for (int j = 0; j < 4; ++j){
        float r  = sigm_((float)xrv[j] + aR[j]);
        float zg = sigm_((float)xzv[j] + aZ[j]);
        float n  = tanh_((float)xnv[j] + r * (aN[j] + bnv[j]));
        float h  = (1.f - zg) * n + zg * hprev[p][j];
        hprev[p][j] = h;
        hh[j] = h;
      }
      unsigned u0 = f2h2(hh[0], hh[1]), u1 = f2h2(hh[2], hh[3]);
      // LDS (next buf), k-chunk layout: chunk = (cb0+16p)>>3, pos = (cb0+16p)&7
      hnext2[((4*w + 2*p + (q >> 1)) * 16 + m) * 2 + (q & 1)] = make_uint2(u0, u1);
      // global: h_t overwrites consumed gx row cols [cb0+16p .. +3]
      *(uint2*)(orow + cb0 + 16 * p) = make_uint2(u0, u1);
    }

    __syncthreads();
    cur ^= 1;
    xr0 = pr0; xz0 = pz0; xn0 = pn0;
    xr1 = pr1; xz1 = pz1; xn1 = pn1;
  }
}

// ---------------------------------------------------------------- phase 3a
// s[m] = sum_a wu[a] * tanh( sum_k outs[m][k]*wv_W[a][k] + wv_b[a] )
__global__ __launch_bounds__(256) void k_score(const f16* __restrict__ outs,
                                               const float* __restrict__ wvW,
                                               const float* __restrict__ wvb,
                                               const float* __restrict__ wu,
                                               float* __restrict__ s){
  __shared__ uint4 OT[32 * 33];
  __shared__ float WV[A_ * 260];
  const int tid = threadIdx.x;
  const int m0 = blockIdx.x * 32;

  #pragma unroll
  for (int u = 0; u < 4; ++u){
    int idx = tid + 256 * u;
    int row = idx >> 5, col = idx & 31;
    OT[row * 33 + col] = *(const uint4*)(outs + (size_t)(m0 + row) * G_ + col * 8);
  }
  #pragma unroll
  for (int u = 0; u < 10; ++u){
    int f = tid + 256 * u;
    int a = f >> 6, k4 = f & 63;
    float4 v = *(const float4*)(wvW + a * 256 + k4 * 4);
    *(float4*)(WV + a * 260 + k4 * 4) = v;
  }
  __syncthreads();

  const int m = tid >> 3, aq = tid & 7;
  float acc[5] = {0.f, 0.f, 0.f, 0.f, 0.f};
  for (int i = 0; i < 32; ++i){
    uint4 oc = OT[m * 33 + i];
    float2 o01 = h2f(oc.x), o23 = h2f(oc.y), o45 = h2f(oc.z), o67 = h2f(oc.w);
    #pragma unroll
    for (int sa = 0; sa < 5; ++sa){
      int a = aq + sa * 8;
      const float* wr = &WV[a * 260 + i * 8];
      float4 w0 = *(const float4*)wr;
      float4 w1 = *(const float4*)(wr + 4);
      acc[sa] += o01.x*w0.x + o01.y*w0.y + o23.x*w0.z + o23.y*w0.w
               + o45.x*w1.x + o45.y*w1.y + o67.x*w1.z + o67.y*w1.w;
    }
  }
  float sp = 0.f;
  #pragma unroll
  for (int sa = 0; sa < 5; ++sa){
    int a = aq + sa * 8;
    sp += wu[a] * tanh_(acc[sa] + wvb[a]);
  }
  sp += __shfl_xor(sp, 1);
  sp += __shfl_xor(sp, 2);
  sp += __shfl_xor(sp, 4);
  if (aq == 0) s[m0 + m] = sp;
}

// ---------------------------------------------------------------- phase 3b
__global__ __launch_bounds__(256) void k_ctx(const f16* __restrict__ outs,
                                             const float* __restrict__ s,
                                             const float* __restrict__ h2oW,
                                             const float* __restrict__ h2ob,
                                             float* __restrict__ out){
  __shared__ float AL[T_];
  __shared__ float red[8];
  const int tid = threadIdx.x;
  const int b = blockIdx.x;
  const float* sb = s + (size_t)b * T_;

  float v0 = sb[tid], v1 = sb[tid + 256], v2 = sb[tid + 512], v3 = sb[tid + 768];
  float mx = fmaxf(fmaxf(v0, v1), fmaxf(v2, v3));
  #pragma unroll
  for (int msk = 1; msk < 64; msk <<= 1) mx = fmaxf(mx, __shfl_xor(mx, msk));
  if ((tid & 63) == 0) red[tid >> 6] = mx;
  __syncthreads();
  mx = fmaxf(fmaxf(red[0], red[1]), fmaxf(red[2], red[3]));

  float e0 = __expf(v0 - mx), e1 = __expf(v1 - mx), e2 = __expf(v2 - mx), e3 = __expf(v3 - mx);
  float zs = e0 + e1 + e2 + e3;
  #pragma unroll
  for (int msk = 1; msk < 64; msk <<= 1) zs += __shfl_xor(zs, msk);
  if ((tid & 63) == 0) red[4 + (tid >> 6)] = zs;
  __syncthreads();
  float invZ = 1.f / (red[4] + red[5] + red[6] + red[7]);
  AL[tid] = e0 * invZ; AL[tid + 256] = e1 * invZ;
  AL[tid + 512] = e2 * invZ; AL[tid + 768] = e3 * invZ;
  __syncthreads();

  const f16* ob = outs + (size_t)b * T_ * G_;
  float acc = 0.f;
  for (int t = 0; t < T_; t += 4){
    acc += AL[t + 0] * (float)ob[(size_t)(t + 0) * G_ + tid];
    acc += AL[t + 1] * (float)ob[(size_t)(t + 1) * G_ + tid];
    acc += AL[t + 2] * (float)ob[(size_t)(t + 2) * G_ + tid];
    acc += AL[t + 3] * (float)ob[(size_t)(t + 3) * G_ + tid];
  }
  __syncthreads();
  float val = acc * h2oW[tid];
  #pragma unroll
  for (int msk = 1; msk < 64; msk <<= 1) val += __shfl_xor(val, msk);
  if ((tid & 63) == 0) red[tid >> 6] = val;
  __syncthreads();
  if (tid == 0) out[b] = red[0] + red[1] + red[2] + red[3] + h2ob[0];
}

// ---------------------------------------------------------------- launch
extern "C" void kernel_launch(void* const* d_in, const int* in_sizes, int n_in,
                              void* d_out, int out_size, void* d_ws, size_t ws_size,
                              hipStream_t stream){
  const float* x    = (const float*)d_in[0];
  const float* wih  = (const float*)d_in[1];
  const float* whh  = (const float*)d_in[2];
  const float* bih  = (const float*)d_in[3];
  const float* bhh  = (const float*)d_in[4];
  const float* wvW  = (const float*)d_in[5];
  const float* wvb  = (const float*)d_in[6];
  const float* wu   = (const float*)d_in[7];
  const float* h2oW = (const float*)d_in[8];
  const float* h2ob = (const float*)d_in[9];
  float* out = (float*)d_out;

  char* ws = (char*)d_ws;
  float*    s  = (float*)ws;                      //     524,288 B
  unsigned* Wp = (unsigned*)(ws + 524288);        //     393,216 B
  unsigned* gx = (unsigned*)(ws + 917504);        // 201,326,592 B

  k_prep_w<<<384, 256, 0, stream>>>(whh, Wp);
  k_gx<<<dim3((B_ * T_) / 64, G_ / 64), 256, 0, stream>>>(x, wih, bih, bhh, gx);
  k_gru<<<8, 512, 0, stream>>>((const uint4*)Wp, gx, bhh);
  k_score<<<(B_ * T_) / 32, 256, 0, stream>>>((const f16*)gx, wvW, wvb, wu, s);
  k_ctx<<<B_, 256, 0, stream>>>((const f16*)gx, s, h2oW, h2ob, out);
}

// Round 5
// 1708.411 us; speedup vs baseline: 2.0835x; 2.0835x over previous
//
#include <hip/hip_runtime.h>

// Att_RNN_GRU: B=128, T=1024, I=128, H=256 (3H=768), A=40
// Phase 1: gx = x @ W_ih^T + b_ih (+b_hh for r,z)  -> f16 [B*T,768]  (MFMA GEMM)
// Phase 2: GRU recurrence, 1 block/batch (128 CUs), 512 thr:
//          thread (g=tid>>1, sub=tid&1) owns rows {g,g+256,g+512}, k-half sub.
//          w register-resident 192 dwords; h in LDS (halves padded 288B apart,
//          conflict-free 2-addr broadcast); reduce = DPP xor-1 add (no LDS);
//          ONE barrier/step. h_t overwrites gx row (b,t)[0:256].
// Phase 3a: s[b,t] = wu . tanh(wv_W @ out + wv_b)   (outs = gx rows, stride 768)
// Phase 3b: softmax over t, context, out = context @ h2o_W^T + b
//
// Workspace: s @0 (512KB), Wp @524288 (384KB), gx @917504 (192MB) = 202.2MB

#define B_ 128
#define T_ 1024
#define I_ 128
#define H_ 256
#define G_ 768
#define A_ 40

typedef _Float16 f16;
typedef _Float16 f16x2 __attribute__((ext_vector_type(2)));
typedef _Float16 f16x8 __attribute__((ext_vector_type(8)));
typedef float    f32x4 __attribute__((ext_vector_type(4)));

__device__ __forceinline__ float fdot2(unsigned a, unsigned b, float c){
#if __has_builtin(__builtin_amdgcn_fdot2)
  return __builtin_amdgcn_fdot2(__builtin_bit_cast(f16x2, a),
                                __builtin_bit_cast(f16x2, b), c, false);
#else
  f16x2 av = __builtin_bit_cast(f16x2, a), bv = __builtin_bit_cast(f16x2, b);
  return c + (float)av.x * (float)bv.x + (float)av.y * (float)bv.y;
#endif
}

__device__ __forceinline__ float2 h2f(unsigned u){
  f16x2 h = __builtin_bit_cast(f16x2, u);
  return make_float2((float)h.x, (float)h.y);
}
__device__ __forceinline__ unsigned f2h2(float a, float b){
  f16x2 h; h.x = (f16)a; h.y = (f16)b;
  return __builtin_bit_cast(unsigned, h);
}
__device__ __forceinline__ float sigm_(float x){ return 1.f / (1.f + __expf(-x)); }
__device__ __forceinline__ float tanh_(float x){ return 1.f - 2.f / (__expf(2.f * x) + 1.f); }

// lane-pair sum via DPP quad_perm(1,0,3,2) — pure VALU, no LDS pipe
__device__ __forceinline__ float xor1_sum(float x){
  int xi = __builtin_bit_cast(int, x);
  int sw = __builtin_amdgcn_update_dpp(0, xi, 0xB1, 0xF, 0xF, true);
  return x + __builtin_bit_cast(float, sw);
}

// ---------------------------------------------------------------- prep W_hh
// Wp[(c*64+d)*512 + tid] = packed f16 pair of W[c*256 + (tid>>1)][ (tid&1)*128 + 2d .. +1 ]
// so k_gru thread `tid` loads its 192 w-dwords fully coalesced.
__global__ __launch_bounds__(256) void k_prep_w(const float* __restrict__ W,
                                                unsigned* __restrict__ Wp){
  int idx = blockIdx.x * 256 + threadIdx.x;      // 0 .. 98303
  int dd  = idx >> 9;                            // 0..191 = c*64+d
  int col = idx & 511;                           // k_gru tid
  int c = dd >> 6, d = dd & 63;
  int g = col >> 1, sub = col & 1;
  int r = c * 256 + g;
  int k = sub * 128 + 2 * d;
  Wp[(size_t)dd * 512 + col] = f2h2(W[r * 256 + k], W[r * 256 + k + 1]);
}

// ---------------------------------------------------------------- phase 1
// MFMA GEMM: gx[m][n] = sum_k x[m][k]*W_ih[n][k] + b_ih[n] + (n<512 ? b_hh[n]:0)
// Block: 256 thr, tile M=128 x N=64, K=128 one-shot in LDS (T2 XOR swizzle).
__global__ __launch_bounds__(256) void k_gx(const float* __restrict__ x,
                                            const float* __restrict__ wih,
                                            const float* __restrict__ bih,
                                            const float* __restrict__ bhh,
                                            f16* __restrict__ gx){
  __shared__ __align__(16) f16 XA[128 * 128];   // [m][k], byte ^= (m&7)<<4
  __shared__ __align__(16) f16 XB[64 * 128];    // [n][k], same swizzle
  const int tid = threadIdx.x;
  const int m0 = blockIdx.x * 128, n0 = blockIdx.y * 64;

  #pragma unroll
  for (int u = 0; u < 16; ++u){
    int idx = tid + 256 * u;                     // 0..4095 float4s
    int row = idx >> 5, k4 = idx & 31;
    float4 v = *(const float4*)(x + (size_t)(m0 + row) * I_ + k4 * 4);
    unsigned byte = (unsigned)(row * 256 + k4 * 8) ^ ((row & 7) << 4);
    *(uint2*)((char*)XA + byte) = make_uint2(f2h2(v.x, v.y), f2h2(v.z, v.w));
  }
  #pragma unroll
  for (int u = 0; u < 8; ++u){
    int idx = tid + 256 * u;                     // 0..2047
    int row = idx >> 5, k4 = idx & 31;
    float4 v = *(const float4*)(wih + (size_t)(n0 + row) * I_ + k4 * 4);
    unsigned byte = (unsigned)(row * 256 + k4 * 8) ^ ((row & 7) << 4);
    *(uint2*)((char*)XB + byte) = make_uint2(f2h2(v.x, v.y), f2h2(v.z, v.w));
  }
  __syncthreads();

  const int l = tid & 63, w = tid >> 6;
  const int q = l >> 4, m16 = l & 15;
  f32x4 acc[2][4];
  #pragma unroll
  for (int i = 0; i < 2; ++i)
    #pragma unroll
    for (int nt = 0; nt < 4; ++nt) acc[i][nt] = (f32x4){0.f, 0.f, 0.f, 0.f};

  #pragma unroll
  for (int kt = 0; kt < 4; ++kt){
    f16x8 af[2];
    #pragma unroll
    for (int i = 0; i < 2; ++i){
      int row = (2 * w + i) * 16 + m16;
      unsigned byte = (unsigned)(row * 256 + kt * 64 + q * 16) ^ ((row & 7) << 4);
      af[i] = *(const f16x8*)((const char*)XA + byte);
    }
    #pragma unroll
    for (int nt = 0; nt < 4; ++nt){
      int row = nt * 16 + m16;
      unsigned byte = (unsigned)(row * 256 + kt * 64 + q * 16) ^ ((row & 7) << 4);
      f16x8 bv = *(const f16x8*)((const char*)XB + byte);
      acc[0][nt] = __builtin_amdgcn_mfma_f32_16x16x32_f16(af[0], bv, acc[0][nt], 0, 0, 0);
      acc[1][nt] = __builtin_amdgcn_mfma_f32_16x16x32_f16(af[1], bv, acc[1][nt], 0, 0, 0);
    }
  }

  float bn[4];
  #pragma unroll
  for (int nt = 0; nt < 4; ++nt){
    int n = n0 + nt * 16 + m16;
    bn[nt] = bih[n] + (n < 512 ? bhh[n] : 0.f);
  }

  __syncthreads();                               // reuse XA as [128][72] staging
  f16* ST = XA;
  #pragma unroll
  for (int i = 0; i < 2; ++i)
    #pragma unroll
    for (int nt = 0; nt < 4; ++nt)
      #pragma unroll
      for (int j = 0; j < 4; ++j){
        int row = (2 * w + i) * 16 + 4 * q + j;  // D row = 4q+j (verified R4)
        ST[row * 72 + nt * 16 + m16] = (f16)(acc[i][nt][j] + bn[nt]);
      }
  __syncthreads();
  #pragma unroll
  for (int u = 0; u < 4; ++u){
    int idx = tid + 256 * u;                     // 0..1023
    int row = idx >> 3, c = idx & 7;
    uint4 v = *(const uint4*)(ST + row * 72 + c * 8);
    *(uint4*)(gx + (size_t)(m0 + row) * G_ + n0 + c * 8) = v;
  }
}

// ---------------------------------------------------------------- phase 2
// 128 blocks x 512 threads. Thread (g,sub): rows {g,g+256,g+512}, k-half sub.
// h in LDS: half0 @ uint4[0..16), half1 @ uint4[18..34) (pad kills conflicts).
// Reduce via DPP xor-1; one barrier per step.
__global__ __launch_bounds__(512, 2) void k_gru(const unsigned* __restrict__ Wp,
                                                unsigned* __restrict__ gx,
                                                const float* __restrict__ bhh){
  __shared__ uint4 hb[2][36];
  const int tid = threadIdx.x;
  const int g = tid >> 1, sub = tid & 1;
  const int b = blockIdx.x;

  unsigned w0[64], w1[64], w2[64];
  #pragma unroll
  for (int d = 0; d < 64; ++d) w0[d] = Wp[(size_t)(d      ) * 512 + tid];
  #pragma unroll
  for (int d = 0; d < 64; ++d) w1[d] = Wp[(size_t)(64  + d) * 512 + tid];
  #pragma unroll
  for (int d = 0; d < 64; ++d) w2[d] = Wp[(size_t)(128 + d) * 512 + tid];

  const float bn_ = bhh[512 + g];
  float hprev = 0.f;
  if (tid < 36) hb[0][tid] = make_uint4(0, 0, 0, 0);

  f16* gxp = (f16*)gx + (size_t)b * T_ * G_;
  float xr = 0.f, xz = 0.f, xn = 0.f;
  if (sub == 0){ xr = (float)gxp[g]; xz = (float)gxp[H_ + g]; xn = (float)gxp[2 * H_ + g]; }
  __syncthreads();

  const int rb = sub * 18;                       // uint4 base of my k-half
  int cur = 0;
  for (int t = 0; t < T_; ++t){
    float pr = 0.f, pz = 0.f, pn = 0.f;          // prefetch t+1 x-terms
    if (sub == 0 && t + 1 < T_){
      const f16* nx = gxp + (size_t)(t + 1) * G_;
      pr = (float)nx[g]; pz = (float)nx[H_ + g]; pn = (float)nx[2 * H_ + g];
    }

    float a00 = 0.f, a01 = 0.f, a10 = 0.f, a11 = 0.f, a20 = 0.f, a21 = 0.f;
    #pragma unroll
    for (int i = 0; i < 16; ++i){
      uint4 hv = hb[cur][rb + i];
      a00 = fdot2(w0[4*i+0], hv.x, a00); a01 = fdot2(w0[4*i+1], hv.y, a01);
      a00 = fdot2(w0[4*i+2], hv.z, a00); a01 = fdot2(w0[4*i+3], hv.w, a01);
      a10 = fdot2(w1[4*i+0], hv.x, a10); a11 = fdot2(w1[4*i+1], hv.y, a11);
      a10 = fdot2(w1[4*i+2], hv.z, a10); a11 = fdot2(w1[4*i+3], hv.w, a11);
      a20 = fdot2(w2[4*i+0], hv.x, a20); a21 = fdot2(w2[4*i+1], hv.y, a21);
      a20 = fdot2(w2[4*i+2], hv.z, a20); a21 = fdot2(w2[4*i+3], hv.w, a21);
    }
    float ar = xor1_sum(a00 + a01);
    float az = xor1_sum(a10 + a11);
    float an = xor1_sum(a20 + a21);

    if (sub == 0){
      float rg = sigm_(xr + ar);                 // b_hh(r,z) folded into gx
      float zg = sigm_(xz + az);
      float ng = tanh_(xn + rg * (an + bn_));
      float h  = (1.f - zg) * ng + zg * hprev;
      hprev = h;
      f16 hh = (f16)h;
      ((f16*)hb[cur ^ 1])[g + (g >> 7) * 16] = hh;   // halves 288B apart
      gxp[(size_t)t * G_ + g] = hh;              // overwrite consumed gx row
      xr = pr; xz = pz; xn = pn;
    }
    __syncthreads();
    cur ^= 1;
  }
}

// ---------------------------------------------------------------- phase 3a
__global__ __launch_bounds__(256) void k_score(const f16* __restrict__ outs,
                                               const float* __restrict__ wvW,
                                               const float* __restrict__ wvb,
                                               const float* __restrict__ wu,
                                               float* __restrict__ s){
  __shared__ uint4 OT[32 * 33];
  __shared__ float WV[A_ * 260];
  const int tid = threadIdx.x;
  const int m0 = blockIdx.x * 32;

  #pragma unroll
  for (int u = 0; u < 4; ++u){
    int idx = tid + 256 * u;
    int row = idx >> 5, col = idx & 31;
    OT[row * 33 + col] = *(const uint4*)(outs + (size_t)(m0 + row) * G_ + col * 8);
  }
  #pragma unroll
  for (int u = 0; u < 10; ++u){
    int f = tid + 256 * u;
    int a = f >> 6, k4 = f & 63;
    float4 v = *(const float4*)(wvW + a * 256 + k4 * 4);
    *(float4*)(WV + a * 260 + k4 * 4) = v;
  }
  __syncthreads();

  const int m = tid >> 3, aq = tid & 7;
  float acc[5] = {0.f, 0.f, 0.f, 0.f, 0.f};
  for (int i = 0; i < 32; ++i){
    uint4 oc = OT[m * 33 + i];
    float2 o01 = h2f(oc.x), o23 = h2f(oc.y), o45 = h2f(oc.z), o67 = h2f(oc.w);
    #pragma unroll
    for (int sa = 0; sa < 5; ++sa){
      int a = aq + sa * 8;
      const float* wr = &WV[a * 260 + i * 8];
      float4 w0 = *(const float4*)wr;
      float4 w1 = *(const float4*)(wr + 4);
      acc[sa] += o01.x*w0.x + o01.y*w0.y + o23.x*w0.z + o23.y*w0.w
               + o45.x*w1.x + o45.y*w1.y + o67.x*w1.z + o67.y*w1.w;
    }
  }
  float sp = 0.f;
  #pragma unroll
  for (int sa = 0; sa < 5; ++sa){
    int a = aq + sa * 8;
    sp += wu[a] * tanh_(acc[sa] + wvb[a]);
  }
  sp += __shfl_xor(sp, 1);
  sp += __shfl_xor(sp, 2);
  sp += __shfl_xor(sp, 4);
  if (aq == 0) s[m0 + m] = sp;
}

// ---------------------------------------------------------------- phase 3b
__global__ __launch_bounds__(256) void k_ctx(const f16* __restrict__ outs,
                                             const float* __restrict__ s,
                                             const float* __restrict__ h2oW,
                                             const float* __restrict__ h2ob,
                                             float* __restrict__ out){
  __shared__ float AL[T_];
  __shared__ float red[8];
  const int tid = threadIdx.x;
  const int b = blockIdx.x;
  const float* sb = s + (size_t)b * T_;

  float v0 = sb[tid], v1 = sb[tid + 256], v2 = sb[tid + 512], v3 = sb[tid + 768];
  float mx = fmaxf(fmaxf(v0, v1), fmaxf(v2, v3));
  #pragma unroll
  for (int msk = 1; msk < 64; msk <<= 1) mx = fmaxf(mx, __shfl_xor(mx, msk));
  if ((tid & 63) == 0) red[tid >> 6] = mx;
  __syncthreads();
  mx = fmaxf(fmaxf(red[0], red[1]), fmaxf(red[2], red[3]));

  float e0 = __expf(v0 - mx), e1 = __expf(v1 - mx), e2 = __expf(v2 - mx), e3 = __expf(v3 - mx);
  float zs = e0 + e1 + e2 + e3;
  #pragma unroll
  for (int msk = 1; msk < 64; msk <<= 1) zs += __shfl_xor(zs, msk);
  if ((tid & 63) == 0) red[4 + (tid >> 6)] = zs;
  __syncthreads();
  float invZ = 1.f / (red[4] + red[5] + red[6] + red[7]);
  AL[tid] = e0 * invZ; AL[tid + 256] = e1 * invZ;
  AL[tid + 512] = e2 * invZ; AL[tid + 768] = e3 * invZ;
  __syncthreads();

  const f16* ob = outs + (size_t)b * T_ * G_;
  float acc = 0.f;
  for (int t = 0; t < T_; t += 4){
    acc += AL[t + 0] * (float)ob[(size_t)(t + 0) * G_ + tid];
    acc += AL[t + 1] * (float)ob[(size_t)(t + 1) * G_ + tid];
    acc += AL[t + 2] * (float)ob[(size_t)(t + 2) * G_ + tid];
    acc += AL[t + 3] * (float)ob[(size_t)(t + 3) * G_ + tid];
  }
  __syncthreads();
  float val = acc * h2oW[tid];
  #pragma unroll
  for (int msk = 1; msk < 64; msk <<= 1) val += __shfl_xor(val, msk);
  if ((tid & 63) == 0) red[tid >> 6] = val;
  __syncthreads();
  if (tid == 0) out[b] = red[0] + red[1] + red[2] + red[3] + h2ob[0];
}

// ---------------------------------------------------------------- launch
extern "C" void kernel_launch(void* const* d_in, const int* in_sizes, int n_in,
                              void* d_out, int out_size, void* d_ws, size_t ws_size,
                              hipStream_t stream){
  const float* x    = (const float*)d_in[0];
  const float* wih  = (const float*)d_in[1];
  const float* whh  = (const float*)d_in[2];
  const float* bih  = (const float*)d_in[3];
  const float* bhh  = (const float*)d_in[4];
  const float* wvW  = (const float*)d_in[5];
  const float* wvb  = (const float*)d_in[6];
  const float* wu   = (const float*)d_in[7];
  const float* h2oW = (const float*)d_in[8];
  const float* h2ob = (const float*)d_in[9];
  float* out = (float*)d_out;

  char* ws = (char*)d_ws;
  float*    s  = (float*)ws;                      //     524,288 B
  unsigned* Wp = (unsigned*)(ws + 524288);        //     393,216 B
  unsigned* gx = (unsigned*)(ws + 917504);        // 201,326,592 B

  k_prep_w<<<384, 256, 0, stream>>>(whh, Wp);
  k_gx<<<dim3((B_ * T_) / 128, G_ / 64), 256, 0, stream>>>(x, wih, bih, bhh, (f16*)gx);
  k_gru<<<B_, 512, 0, stream>>>(Wp, gx, bhh);
  k_score<<<(B_ * T_) / 32, 256, 0, stream>>>((const f16*)gx, wvW, wvb, wu, s);
  k_ctx<<<B_, 256, 0, stream>>>((const f16*)gx, s, h2oW, h2ob, out);
}